// Round 1
// baseline (514.774 us; speedup 1.0000x reference)
//
#include <hip/hip_runtime.h>
#include <hip/hip_bf16.h>

#define Td 4096
#define Hd 1024
#define Fd 2048
#define Ed 8

#define BM 128
#define BN 128
#define BK 32
#define LDA 40  // padded LDS row stride in bf16 elems (80B, 16B-aligned)

typedef short bf16x8 __attribute__((ext_vector_type(8)));
typedef float f32x4 __attribute__((ext_vector_type(4)));

__device__ __forceinline__ unsigned short f2bf(float f) {
  union { float f; unsigned u; } v; v.f = f;
  unsigned r = v.u + 0x7FFFu + ((v.u >> 16) & 1u);
  return (unsigned short)(r >> 16);
}

// ---------------- prep: transpose + fp32->bf16 all expert weights ----------
// gate/up: src [Hd][Fd] -> dst [Fd][Hd]; down: src [Fd][Hd] -> dst [Hd][Fd]
__global__ void prep_transpose_kernel(const float* __restrict__ gw,
                                      const float* __restrict__ uw,
                                      const float* __restrict__ dw,
                                      unsigned short* __restrict__ gt,
                                      unsigned short* __restrict__ ut,
                                      unsigned short* __restrict__ dt) {
  const int m = blockIdx.z % 3;
  const int e = blockIdx.z / 3;
  const int R = (m == 2) ? Fd : Hd;   // src rows
  const int C = (m == 2) ? Hd : Fd;   // src cols
  const int r0 = blockIdx.y * 64, c0 = blockIdx.x * 64;
  if (r0 >= R || c0 >= C) return;
  const float* src = ((m == 0) ? gw : (m == 1) ? uw : dw) + (size_t)e * Hd * Fd;
  unsigned short* dst = ((m == 0) ? gt : (m == 1) ? ut : dt) + (size_t)e * Hd * Fd;
  __shared__ unsigned short tile[64][68];
  const int tr = threadIdx.x >> 4;          // 0..15
  const int tc = (threadIdx.x & 15) * 4;    // 0..60
#pragma unroll
  for (int i = 0; i < 4; ++i) {
    const int r = tr + i * 16;
    const float4 v = *(const float4*)(src + (size_t)(r0 + r) * C + c0 + tc);
    tile[r][tc + 0] = f2bf(v.x);
    tile[r][tc + 1] = f2bf(v.y);
    tile[r][tc + 2] = f2bf(v.z);
    tile[r][tc + 3] = f2bf(v.w);
  }
  __syncthreads();
#pragma unroll
  for (int i = 0; i < 4; ++i) {
    const int c = tr + i * 16;              // dst row = src col
    ushort4 o;
    o.x = tile[tc + 0][c];
    o.y = tile[tc + 1][c];
    o.z = tile[tc + 2][c];
    o.w = tile[tc + 3][c];
    *(ushort4*)(dst + (size_t)(c0 + c) * R + r0 + tc) = o;
  }
}

// ---------------- routing: build compacted per-expert (token, coeff) lists --
__global__ void routing_kernel(const int* __restrict__ ids,
                               const float* __restrict__ w,
                               int* __restrict__ cnt, int* __restrict__ base,
                               int* __restrict__ tok, float* __restrict__ cof) {
  __shared__ int lcnt[Ed], lbase[Ed], lpos[Ed];
  const int t = threadIdx.x;
  if (t < Ed) { lcnt[t] = 0; lpos[t] = 0; }
  __syncthreads();
  for (int i = t; i < Td; i += blockDim.x) {
    const int e0 = ids[i * 2], e1 = ids[i * 2 + 1];
    atomicAdd(&lcnt[e0], 1);
    if (e1 != e0) atomicAdd(&lcnt[e1], 1);
  }
  __syncthreads();
  if (t == 0) {
    int s = 0;
    for (int e = 0; e < Ed; ++e) { lbase[e] = s; s += lcnt[e]; }
  }
  __syncthreads();
  for (int i = t; i < Td; i += blockDim.x) {
    const int e0 = ids[i * 2], e1 = ids[i * 2 + 1];
    const float w0 = w[i * 2], w1 = w[i * 2 + 1];
    if (e0 == e1) {
      const int p = atomicAdd(&lpos[e0], 1);
      tok[lbase[e0] + p] = i; cof[lbase[e0] + p] = w0 + w1;
    } else {
      int p = atomicAdd(&lpos[e0], 1);
      tok[lbase[e0] + p] = i; cof[lbase[e0] + p] = w0;
      p = atomicAdd(&lpos[e1], 1);
      tok[lbase[e1] + p] = i; cof[lbase[e1] + p] = w1;
    }
  }
  __syncthreads();
  if (t < Ed) { cnt[t] = lcnt[t]; base[t] = lbase[t]; }
}

// ---------------- grouped gate/up GEMM + silu*u*coeff -> act (bf16) ---------
__global__ __launch_bounds__(256)
void gateup_kernel(const float* __restrict__ x,
                   const unsigned short* __restrict__ gate_t,
                   const unsigned short* __restrict__ up_t,
                   const int* __restrict__ cnt, const int* __restrict__ base,
                   const int* __restrict__ tok, const float* __restrict__ cof,
                   unsigned short* __restrict__ act) {
  const int e = blockIdx.z, mt = blockIdx.y, nt = blockIdx.x;
  const int cn = cnt[e];
  if (mt * BM >= cn) return;
  const int b0 = base[e];

  __shared__ unsigned short A_lds[BM][LDA];
  __shared__ unsigned short Bg_lds[BN][LDA];
  __shared__ unsigned short Bu_lds[BN][LDA];
  __shared__ int tok_l[BM];
  __shared__ float cof_l[BM];

  const int tid = threadIdx.x;
  if (tid < BM) {
    const int r = mt * BM + tid;
    tok_l[tid] = (r < cn) ? tok[b0 + r] : 0;
    cof_l[tid] = (r < cn) ? cof[b0 + r] : 0.f;
  }

  const unsigned short* gp = gate_t + (size_t)e * Fd * Hd + (size_t)(nt * BN) * Hd;
  const unsigned short* upw = up_t  + (size_t)e * Fd * Hd + (size_t)(nt * BN) * Hd;

  const int lane = tid & 63;
  const int wave = tid >> 6;       // 4 waves: 2x2 over 64x64 subtiles
  const int wm = wave >> 1;
  const int wn = wave & 1;
  const int fr16 = lane & 15;
  const int k8 = (lane >> 4) * 8;

  f32x4 accg[4][4], accu[4][4];
#pragma unroll
  for (int i = 0; i < 4; ++i)
#pragma unroll
    for (int j = 0; j < 4; ++j) {
      accg[i][j] = (f32x4){0.f, 0.f, 0.f, 0.f};
      accu[i][j] = (f32x4){0.f, 0.f, 0.f, 0.f};
    }

  const int sr = tid >> 1;            // staging row 0..127
  const int sk = (tid & 1) * 16;      // k-half
  const bool rvalid = (mt * BM + sr) < cn;

  __syncthreads();  // tok_l/cof_l ready
  const size_t xoff = (size_t)tok_l[sr] * Hd + sk;

  for (int k0 = 0; k0 < Hd; k0 += BK) {
    __syncthreads();  // previous tile consumed
    // A: gathered x rows, fp32 -> bf16
    {
      bf16x8 t0 = 0, t1 = 0;
      if (rvalid) {
        const float* xp = x + xoff + k0;
        const float4 v0 = *(const float4*)(xp + 0);
        const float4 v1 = *(const float4*)(xp + 4);
        const float4 v2 = *(const float4*)(xp + 8);
        const float4 v3 = *(const float4*)(xp + 12);
        t0[0] = (short)f2bf(v0.x); t0[1] = (short)f2bf(v0.y);
        t0[2] = (short)f2bf(v0.z); t0[3] = (short)f2bf(v0.w);
        t0[4] = (short)f2bf(v1.x); t0[5] = (short)f2bf(v1.y);
        t0[6] = (short)f2bf(v1.z); t0[7] = (short)f2bf(v1.w);
        t1[0] = (short)f2bf(v2.x); t1[1] = (short)f2bf(v2.y);
        t1[2] = (short)f2bf(v2.z); t1[3] = (short)f2bf(v2.w);
        t1[4] = (short)f2bf(v3.x); t1[5] = (short)f2bf(v3.y);
        t1[6] = (short)f2bf(v3.z); t1[7] = (short)f2bf(v3.w);
      }
      *(bf16x8*)&A_lds[sr][sk + 0] = t0;
      *(bf16x8*)&A_lds[sr][sk + 8] = t1;
    }
    // B gate + up: already bf16, K-inner
    {
      const unsigned short* g1 = gp  + (size_t)sr * Hd + k0 + sk;
      const unsigned short* u1 = upw + (size_t)sr * Hd + k0 + sk;
      *(uint4*)&Bg_lds[sr][sk + 0] = *(const uint4*)(g1 + 0);
      *(uint4*)&Bg_lds[sr][sk + 8] = *(const uint4*)(g1 + 8);
      *(uint4*)&Bu_lds[sr][sk + 0] = *(const uint4*)(u1 + 0);
      *(uint4*)&Bu_lds[sr][sk + 8] = *(const uint4*)(u1 + 8);
    }
    __syncthreads();

    bf16x8 af[4], bg[4], bu[4];
#pragma unroll
    for (int f = 0; f < 4; ++f)
      af[f] = *(const bf16x8*)&A_lds[wm * 64 + f * 16 + fr16][k8];
#pragma unroll
    for (int f = 0; f < 4; ++f) {
      bg[f] = *(const bf16x8*)&Bg_lds[wn * 64 + f * 16 + fr16][k8];
      bu[f] = *(const bf16x8*)&Bu_lds[wn * 64 + f * 16 + fr16][k8];
    }
#pragma unroll
    for (int fm = 0; fm < 4; ++fm)
#pragma unroll
      for (int fn = 0; fn < 4; ++fn) {
        accg[fm][fn] = __builtin_amdgcn_mfma_f32_16x16x32_bf16(af[fm], bg[fn], accg[fm][fn], 0, 0, 0);
        accu[fm][fn] = __builtin_amdgcn_mfma_f32_16x16x32_bf16(af[fm], bu[fn], accu[fm][fn], 0, 0, 0);
      }
  }

  // epilogue: act = silu(g)*u*coeff, bf16 store (C layout: col=lane&15, row=(lane>>4)*4+reg)
  const int row4 = (lane >> 4) * 4;
#pragma unroll
  for (int fm = 0; fm < 4; ++fm) {
#pragma unroll
    for (int fn = 0; fn < 4; ++fn) {
#pragma unroll
      for (int r = 0; r < 4; ++r) {
        const int rr = wm * 64 + fm * 16 + row4 + r;      // row in tile
        const int grow = mt * BM + rr;
        if (grow < cn) {
          const float g = accg[fm][fn][r];
          const float u = accu[fm][fn][r];
          const float a = (g / (1.f + __expf(-g))) * u * cof_l[rr];
          const int col = nt * BN + wn * 64 + fn * 16 + fr16;
          act[(size_t)(b0 + grow) * Fd + col] = f2bf(a);
        }
      }
    }
  }
}

// ---------------- grouped down GEMM + atomic scatter into out ---------------
__global__ __launch_bounds__(256)
void down_kernel(const unsigned short* __restrict__ act,
                 const unsigned short* __restrict__ down_t,
                 const int* __restrict__ cnt, const int* __restrict__ base,
                 const int* __restrict__ tok,
                 float* __restrict__ out) {
  const int e = blockIdx.z, mt = blockIdx.y, nt = blockIdx.x;
  const int cn = cnt[e];
  if (mt * BM >= cn) return;
  const int b0 = base[e];

  __shared__ unsigned short A_lds[BM][LDA];
  __shared__ unsigned short B_lds[BN][LDA];
  __shared__ int tok_l[BM];

  const int tid = threadIdx.x;
  if (tid < BM) {
    const int r = mt * BM + tid;
    tok_l[tid] = (r < cn) ? tok[b0 + r] : 0;
  }

  const unsigned short* dp = down_t + (size_t)e * Hd * Fd + (size_t)(nt * BN) * Fd;

  const int lane = tid & 63;
  const int wave = tid >> 6;
  const int wm = wave >> 1;
  const int wn = wave & 1;
  const int fr16 = lane & 15;
  const int k8 = (lane >> 4) * 8;

  f32x4 acc[4][4];
#pragma unroll
  for (int i = 0; i < 4; ++i)
#pragma unroll
    for (int j = 0; j < 4; ++j) acc[i][j] = (f32x4){0.f, 0.f, 0.f, 0.f};

  const int sr = tid >> 1;
  const int sk = (tid & 1) * 16;
  const bool rvalid = (mt * BM + sr) < cn;
  const size_t arow = (size_t)(b0 + mt * BM + sr) * Fd + sk;

  for (int k0 = 0; k0 < Fd; k0 += BK) {
    __syncthreads();
    {
      bf16x8 t0 = 0, t1 = 0;
      if (rvalid) {
        const unsigned short* ap = act + arow + k0;
        t0 = *(const bf16x8*)(ap + 0);
        t1 = *(const bf16x8*)(ap + 8);
      }
      *(bf16x8*)&A_lds[sr][sk + 0] = t0;
      *(bf16x8*)&A_lds[sr][sk + 8] = t1;
      const unsigned short* bp = dp + (size_t)sr * Fd + k0 + sk;
      *(uint4*)&B_lds[sr][sk + 0] = *(const uint4*)(bp + 0);
      *(uint4*)&B_lds[sr][sk + 8] = *(const uint4*)(bp + 8);
    }
    __syncthreads();

    bf16x8 af[4], bf[4];
#pragma unroll
    for (int f = 0; f < 4; ++f) {
      af[f] = *(const bf16x8*)&A_lds[wm * 64 + f * 16 + fr16][k8];
      bf[f] = *(const bf16x8*)&B_lds[wn * 64 + f * 16 + fr16][k8];
    }
#pragma unroll
    for (int fm = 0; fm < 4; ++fm)
#pragma unroll
      for (int fn = 0; fn < 4; ++fn)
        acc[fm][fn] = __builtin_amdgcn_mfma_f32_16x16x32_bf16(af[fm], bf[fn], acc[fm][fn], 0, 0, 0);
  }

  const int row4 = (lane >> 4) * 4;
#pragma unroll
  for (int fm = 0; fm < 4; ++fm) {
#pragma unroll
    for (int fn = 0; fn < 4; ++fn) {
#pragma unroll
      for (int r = 0; r < 4; ++r) {
        const int rr = wm * 64 + fm * 16 + row4 + r;
        if (mt * BM + rr < cn) {
          const int col = nt * BN + wn * 64 + fn * 16 + fr16;
          atomicAdd(&out[(size_t)tok_l[rr] * Hd + col], acc[fm][fn][r]);
        }
      }
    }
  }
}

extern "C" void kernel_launch(void* const* d_in, const int* in_sizes, int n_in,
                              void* d_out, int out_size, void* d_ws, size_t ws_size,
                              hipStream_t stream) {
  const float* x  = (const float*)d_in[0];
  const int*   ids = (const int*)d_in[1];
  const float* w  = (const float*)d_in[2];
  const float* gw = (const float*)d_in[3];
  const float* uw = (const float*)d_in[4];
  const float* dw = (const float*)d_in[5];
  float* out = (float*)d_out;

  // ws layout: gate_t | up_t | down_t (bf16, 32MB each) | act (8192xFd bf16, 32MB) | meta
  const size_t SZW = (size_t)Ed * Hd * Fd * 2;
  char* ws = (char*)d_ws;
  unsigned short* gt  = (unsigned short*)(ws);
  unsigned short* ut  = (unsigned short*)(ws + SZW);
  unsigned short* dt  = (unsigned short*)(ws + 2 * SZW);
  unsigned short* act = (unsigned short*)(ws + 3 * SZW);
  char* meta = ws + 3 * SZW + (size_t)8192 * Fd * 2;
  int*   cnt  = (int*)meta;
  int*   base = (int*)(meta + 32);
  int*   tok  = (int*)(meta + 64);
  float* cof  = (float*)(meta + 64 + 8192 * 4);

  hipMemsetAsync(d_out, 0, (size_t)Td * Hd * 4, stream);
  prep_transpose_kernel<<<dim3(32, 32, 24), 256, 0, stream>>>(gw, uw, dw, gt, ut, dt);
  routing_kernel<<<1, 1024, 0, stream>>>(ids, w, cnt, base, tok, cof);
  gateup_kernel<<<dim3(Fd / BN, Td / BM, Ed), 256, 0, stream>>>(x, gt, ut, cnt, base, tok, cof, act);
  down_kernel<<<dim3(Hd / BN, Td / BM, Ed), 256, 0, stream>>>(act, dt, cnt, base, tok, out);
}

// Round 3
// 439.608 us; speedup vs baseline: 1.1710x; 1.1710x over previous
//
#include <hip/hip_runtime.h>
#include <hip/hip_bf16.h>

#define Td 4096
#define Hd 1024
#define Fd 2048
#define Ed 8
#define BM 128
#define BN 128
#define BK 64

typedef short bf16x8 __attribute__((ext_vector_type(8)));
typedef float f32x4 __attribute__((ext_vector_type(4)));

__device__ __forceinline__ unsigned short f2bf(float f) {
  union { float f; unsigned u; } v; v.f = f;
  unsigned r = v.u + 0x7FFFu + ((v.u >> 16) & 1u);
  return (unsigned short)(r >> 16);
}

// global -> LDS direct DMA, 16B per lane. LDS dest = wave-uniform base + lane*16.
// Canonical addrspace casts (pointer->pointer addrspacecast, no integer trunc).
__device__ __forceinline__ void gload16(const unsigned short* g, unsigned short* l) {
  __builtin_amdgcn_global_load_lds(
      (const __attribute__((address_space(1))) unsigned int*)g,
      (__attribute__((address_space(3))) unsigned int*)l,
      16, 0, 0);
}

// ---------------- x fp32 -> bf16 ----------------
__global__ void xconv_kernel(const float* __restrict__ x, unsigned short* __restrict__ xb) {
  const int i = (blockIdx.x * 256 + threadIdx.x) * 8;
  const float4 v0 = *(const float4*)(x + i);
  const float4 v1 = *(const float4*)(x + i + 4);
  bf16x8 o;
  o[0] = (short)f2bf(v0.x); o[1] = (short)f2bf(v0.y);
  o[2] = (short)f2bf(v0.z); o[3] = (short)f2bf(v0.w);
  o[4] = (short)f2bf(v1.x); o[5] = (short)f2bf(v1.y);
  o[6] = (short)f2bf(v1.z); o[7] = (short)f2bf(v1.w);
  *(bf16x8*)(xb + i) = o;
}

// ---------------- prep: transpose + fp32->bf16 all expert weights ----------
__global__ void prep_transpose_kernel(const float* __restrict__ gw,
                                      const float* __restrict__ uw,
                                      const float* __restrict__ dw,
                                      unsigned short* __restrict__ gt,
                                      unsigned short* __restrict__ ut,
                                      unsigned short* __restrict__ dt) {
  const int m = blockIdx.z % 3;
  const int e = blockIdx.z / 3;
  const int R = (m == 2) ? Fd : Hd;
  const int C = (m == 2) ? Hd : Fd;
  const int r0 = blockIdx.y * 64, c0 = blockIdx.x * 64;
  if (r0 >= R || c0 >= C) return;
  const float* src = ((m == 0) ? gw : (m == 1) ? uw : dw) + (size_t)e * Hd * Fd;
  unsigned short* dst = ((m == 0) ? gt : (m == 1) ? ut : dt) + (size_t)e * Hd * Fd;
  __shared__ unsigned short tile[64][68];
  const int tr = threadIdx.x >> 4;
  const int tc = (threadIdx.x & 15) * 4;
#pragma unroll
  for (int i = 0; i < 4; ++i) {
    const int r = tr + i * 16;
    const float4 v = *(const float4*)(src + (size_t)(r0 + r) * C + c0 + tc);
    tile[r][tc + 0] = f2bf(v.x);
    tile[r][tc + 1] = f2bf(v.y);
    tile[r][tc + 2] = f2bf(v.z);
    tile[r][tc + 3] = f2bf(v.w);
  }
  __syncthreads();
#pragma unroll
  for (int i = 0; i < 4; ++i) {
    const int c = tr + i * 16;
    ushort4 o;
    o.x = tile[tc + 0][c];
    o.y = tile[tc + 1][c];
    o.z = tile[tc + 2][c];
    o.w = tile[tc + 3][c];
    *(ushort4*)(dst + (size_t)(c0 + c) * R + r0 + tc) = o;
  }
}

// ---------------- routing: wave-aggregated per-expert lists ----------------
__global__ void routing_kernel(const int* __restrict__ ids,
                               const float* __restrict__ w,
                               int* __restrict__ cnt, int* __restrict__ base,
                               int* __restrict__ tok, float* __restrict__ cof) {
  __shared__ int lcnt[Ed], lbase[Ed], lpos[Ed];
  const int t = threadIdx.x;            // 1024 threads = 16 waves
  const int lane = t & 63;
  if (t < Ed) { lcnt[t] = 0; lpos[t] = 0; }
  __syncthreads();
  for (int i = t; i < Td; i += 1024) {
    const int e0 = ids[2 * i], e1 = ids[2 * i + 1];
    const int em = (e1 == e0) ? -1 : e1;
#pragma unroll
    for (int e = 0; e < Ed; ++e) {
      unsigned long long m0 = __ballot(e0 == e);
      unsigned long long m1 = __ballot(em == e);
      int n = __popcll(m0) + __popcll(m1);
      if (lane == 0 && n) atomicAdd(&lcnt[e], n);
    }
  }
  __syncthreads();
  if (t == 0) {
    int s = 0;
    for (int e = 0; e < Ed; ++e) { lbase[e] = s; s += lcnt[e]; }
  }
  __syncthreads();
  const unsigned long long below = (1ull << lane) - 1ull;
  for (int i = t; i < Td; i += 1024) {
    const int e0 = ids[2 * i], e1 = ids[2 * i + 1];
    const float w0 = w[2 * i], w1 = w[2 * i + 1];
    const bool mg = (e1 == e0);
    const int em = mg ? -1 : e1;
#pragma unroll
    for (int e = 0; e < Ed; ++e) {
      unsigned long long m0 = __ballot(e0 == e);
      unsigned long long m1 = __ballot(em == e);
      const int n0 = __popcll(m0);
      const int n = n0 + __popcll(m1);
      int p = 0;
      if (lane == 0 && n) p = atomicAdd(&lpos[e], n);
      p = __shfl(p, 0);
      if (e0 == e) {
        const int r = lbase[e] + p + __popcll(m0 & below);
        tok[r] = i; cof[r] = mg ? (w0 + w1) : w0;
      }
      if (em == e) {
        const int r = lbase[e] + p + n0 + __popcll(m1 & below);
        tok[r] = i; cof[r] = w1;
      }
    }
  }
  __syncthreads();
  if (t < Ed) { cnt[t] = lcnt[t]; base[t] = lbase[t]; }
}

// ---------------- grouped gate/up GEMM + silu*u*coeff -> act (bf16) ---------
// LDS tiles [128][64] bf16, XOR-swizzled: data for (row, kslot j) lives at
// 16B-slot (j ^ (row&7)). global_load_lds writes linearly; the per-lane
// GLOBAL source address carries the inverse swizzle (rule 21 / m201 pattern).
__global__ __launch_bounds__(256)
void gateup_kernel(const unsigned short* __restrict__ xb,
                   const unsigned short* __restrict__ gate_t,
                   const int* __restrict__ cnt, const int* __restrict__ base,
                   const int* __restrict__ tok, const float* __restrict__ cof,
                   unsigned short* __restrict__ act) {
  const int e = blockIdx.z, mt = blockIdx.y, nt = blockIdx.x;
  const int cn = cnt[e];
  if (mt * BM >= cn) return;
  const int b0 = base[e];

  __shared__ unsigned short A_lds[BM * BK];
  __shared__ unsigned short Bg_lds[BN * BK];
  __shared__ unsigned short Bu_lds[BN * BK];
  __shared__ int tok_l[BM];
  __shared__ float cof_l[BM];

  const int tid = threadIdx.x;
  if (tid < BM) {
    const int r = mt * BM + tid;
    tok_l[tid] = (r < cn) ? tok[b0 + r] : 0;
    cof_l[tid] = (r < cn) ? cof[b0 + r] : 0.f;
  }
  __syncthreads();

  const int lane = tid & 63;
  const int wave = tid >> 6;
  const int wm = wave >> 1, wn = wave & 1;
  const int fr16 = lane & 15;
  const int jb = lane >> 4;        // k 16B-slot base (0..3), kk adds 4
  const int rx7 = lane & 7;        // == (frag row) & 7

  // per-lane staging source: lds row rl = wave*32 + i*8 + (lane>>3),
  // lds slot s = lane&7 holds global kslot j = s ^ (rl&7) = (lane&7)^(lane>>3)
  const int sw = ((lane & 7) ^ (lane >> 3)) * 8;
  const unsigned short* gwp = gate_t + (size_t)e * Fd * Hd;
  const unsigned short* ap[4];
  const unsigned short* gp[4];
#pragma unroll
  for (int i = 0; i < 4; ++i) {
    const int rl = wave * 32 + i * 8 + (lane >> 3);
    ap[i] = xb + (size_t)tok_l[rl] * Hd + sw;
    gp[i] = gwp + (size_t)(nt * BN + rl) * Hd + sw;
  }
  const size_t UPOFF = (size_t)Ed * Fd * Hd;  // up_t = gate_t + UPOFF elems

  f32x4 accg[4][4], accu[4][4];
#pragma unroll
  for (int i = 0; i < 4; ++i)
#pragma unroll
    for (int j = 0; j < 4; ++j) {
      accg[i][j] = (f32x4){0.f, 0.f, 0.f, 0.f};
      accu[i][j] = (f32x4){0.f, 0.f, 0.f, 0.f};
    }

  for (int k0 = 0; k0 < Hd; k0 += BK) {
    __syncthreads();
#pragma unroll
    for (int i = 0; i < 4; ++i) {
      gload16(ap[i] + k0,         A_lds  + wave * 2048 + i * 512);
      gload16(gp[i] + k0,         Bg_lds + wave * 2048 + i * 512);
      gload16(gp[i] + UPOFF + k0, Bu_lds + wave * 2048 + i * 512);
    }
    __syncthreads();
#pragma unroll
    for (int kk = 0; kk < 2; ++kk) {
      bf16x8 af[4], bg[4], bu[4];
      const int slot = kk * 4 + jb;
#pragma unroll
      for (int f = 0; f < 4; ++f) {
        const int ra = wm * 64 + f * 16 + fr16;
        const int rb = wn * 64 + f * 16 + fr16;
        af[f] = *(const bf16x8*)&A_lds [64 * ra + 8 * (slot ^ rx7)];
        bg[f] = *(const bf16x8*)&Bg_lds[64 * rb + 8 * (slot ^ rx7)];
        bu[f] = *(const bf16x8*)&Bu_lds[64 * rb + 8 * (slot ^ rx7)];
      }
#pragma unroll
      for (int fm = 0; fm < 4; ++fm)
#pragma unroll
        for (int fn = 0; fn < 4; ++fn) {
          accg[fm][fn] = __builtin_amdgcn_mfma_f32_16x16x32_bf16(af[fm], bg[fn], accg[fm][fn], 0, 0, 0);
          accu[fm][fn] = __builtin_amdgcn_mfma_f32_16x16x32_bf16(af[fm], bu[fn], accu[fm][fn], 0, 0, 0);
        }
    }
  }

  const int row4 = (lane >> 4) * 4;
#pragma unroll
  for (int fm = 0; fm < 4; ++fm) {
#pragma unroll
    for (int fn = 0; fn < 4; ++fn) {
#pragma unroll
      for (int r = 0; r < 4; ++r) {
        const int rr = wm * 64 + fm * 16 + row4 + r;
        const int grow = mt * BM + rr;
        if (grow < cn) {
          const float g = accg[fm][fn][r];
          const float u = accu[fm][fn][r];
          const float a = (g / (1.f + __expf(-g))) * u * cof_l[rr];
          const int col = nt * BN + wn * 64 + fn * 16 + fr16;
          act[(size_t)(b0 + grow) * Fd + col] = f2bf(a);
        }
      }
    }
  }
}

// ---------------- grouped down GEMM + atomic scatter into out ---------------
__global__ __launch_bounds__(256)
void down_kernel(const unsigned short* __restrict__ act,
                 const unsigned short* __restrict__ down_t,
                 const int* __restrict__ cnt, const int* __restrict__ base,
                 const int* __restrict__ tok,
                 float* __restrict__ out) {
  const int e = blockIdx.z, mt = blockIdx.y, nt = blockIdx.x;
  const int cn = cnt[e];
  if (mt * BM >= cn) return;
  const int b0 = base[e];

  __shared__ unsigned short A_lds[BM * BK];
  __shared__ unsigned short B_lds[BN * BK];
  __shared__ int tok_l[BM];

  const int tid = threadIdx.x;
  if (tid < BM) {
    const int r = mt * BM + tid;
    tok_l[tid] = (r < cn) ? tok[b0 + r] : 0;
  }

  const int lane = tid & 63;
  const int wave = tid >> 6;
  const int wm = wave >> 1, wn = wave & 1;
  const int fr16 = lane & 15;
  const int jb = lane >> 4;
  const int rx7 = lane & 7;

  const int sw = ((lane & 7) ^ (lane >> 3)) * 8;
  const unsigned short* dwp = down_t + (size_t)e * Hd * Fd;
  const unsigned short* ap[4];
  const unsigned short* bp[4];
#pragma unroll
  for (int i = 0; i < 4; ++i) {
    const int rl = wave * 32 + i * 8 + (lane >> 3);
    int rowg = b0 + mt * BM + rl;
    if (rowg > 8191) rowg = 8191;     // stay inside act buffer
    ap[i] = act + (size_t)rowg * Fd + sw;
    bp[i] = dwp + (size_t)(nt * BN + rl) * Fd + sw;
  }

  f32x4 acc[4][4];
#pragma unroll
  for (int i = 0; i < 4; ++i)
#pragma unroll
    for (int j = 0; j < 4; ++j) acc[i][j] = (f32x4){0.f, 0.f, 0.f, 0.f};

  for (int k0 = 0; k0 < Fd; k0 += BK) {
    __syncthreads();
#pragma unroll
    for (int i = 0; i < 4; ++i) {
      gload16(ap[i] + k0, A_lds + wave * 2048 + i * 512);
      gload16(bp[i] + k0, B_lds + wave * 2048 + i * 512);
    }
    __syncthreads();
#pragma unroll
    for (int kk = 0; kk < 2; ++kk) {
      bf16x8 af[4], bf[4];
      const int slot = kk * 4 + jb;
#pragma unroll
      for (int f = 0; f < 4; ++f) {
        const int ra = wm * 64 + f * 16 + fr16;
        const int rb = wn * 64 + f * 16 + fr16;
        af[f] = *(const bf16x8*)&A_lds[64 * ra + 8 * (slot ^ rx7)];
        bf[f] = *(const bf16x8*)&B_lds[64 * rb + 8 * (slot ^ rx7)];
      }
#pragma unroll
      for (int fm = 0; fm < 4; ++fm)
#pragma unroll
        for (int fn = 0; fn < 4; ++fn)
          acc[fm][fn] = __builtin_amdgcn_mfma_f32_16x16x32_bf16(af[fm], bf[fn], acc[fm][fn], 0, 0, 0);
    }
  }

  const int row4 = (lane >> 4) * 4;
#pragma unroll
  for (int fm = 0; fm < 4; ++fm) {
#pragma unroll
    for (int fn = 0; fn < 4; ++fn) {
#pragma unroll
      for (int r = 0; r < 4; ++r) {
        const int rr = wm * 64 + fm * 16 + row4 + r;
        if (mt * BM + rr < cn) {
          const int col = nt * BN + wn * 64 + fn * 16 + fr16;
          atomicAdd(&out[(size_t)tok_l[rr] * Hd + col], acc[fm][fn][r]);
        }
      }
    }
  }
}

extern "C" void kernel_launch(void* const* d_in, const int* in_sizes, int n_in,
                              void* d_out, int out_size, void* d_ws, size_t ws_size,
                              hipStream_t stream) {
  const float* x  = (const float*)d_in[0];
  const int*   ids = (const int*)d_in[1];
  const float* w  = (const float*)d_in[2];
  const float* gw = (const float*)d_in[3];
  const float* uw = (const float*)d_in[4];
  const float* dw = (const float*)d_in[5];
  float* out = (float*)d_out;

  // ws: gate_t | up_t | down_t (bf16 32MB ea) | act (8192xFd bf16 32MB) | xb (8MB) | meta
  const size_t SZW = (size_t)Ed * Hd * Fd * 2;
  const size_t ACT = (size_t)8192 * Fd * 2;
  const size_t XB  = (size_t)Td * Hd * 2;
  const size_t NEED = 3 * SZW + ACT + XB + 1 * 1024 * 1024;
  if (ws_size < NEED) return;  // diagnostic: absmax-fail loudly instead of OOB-faulting

  char* ws = (char*)d_ws;
  unsigned short* gt   = (unsigned short*)(ws);
  unsigned short* ut   = (unsigned short*)(ws + SZW);
  unsigned short* dt   = (unsigned short*)(ws + 2 * SZW);
  unsigned short* act  = (unsigned short*)(ws + 3 * SZW);
  unsigned short* xbuf = (unsigned short*)(ws + 3 * SZW + ACT);
  char* meta = ws + 3 * SZW + ACT + XB;
  int*   cnt  = (int*)meta;
  int*   base = (int*)(meta + 32);
  int*   tok  = (int*)(meta + 64);
  float* cof  = (float*)(meta + 64 + 8192 * 4);

  hipMemsetAsync(d_out, 0, (size_t)Td * Hd * 4, stream);
  xconv_kernel<<<Td * Hd / 8 / 256, 256, 0, stream>>>(x, xbuf);
  routing_kernel<<<1, 1024, 0, stream>>>(ids, w, cnt, base, tok, cof);
  prep_transpose_kernel<<<dim3(32, 32, 24), 256, 0, stream>>>(gw, uw, dw, gt, ut, dt);
  gateup_kernel<<<dim3(Fd / BN, Td / BM, Ed), 256, 0, stream>>>(xbuf, gt, cnt, base, tok, cof, act);
  down_kernel<<<dim3(Hd / BN, Td / BM, Ed), 256, 0, stream>>>(act, dt, cnt, base, tok, out);
}

// Round 4
// 428.613 us; speedup vs baseline: 1.2010x; 1.0257x over previous
//
#include <hip/hip_runtime.h>
#include <hip/hip_bf16.h>

#define Td 4096
#define Hd 1024
#define Fd 2048
#define Ed 8

// GEMM geometry: 256x128 tile, BK=32, 4 waves (2m x 2n), wave = 128x64.
// LDS: 3 K-tile slots (triple buffer) -> stage T+2 while computing T.
// vmcnt ledger (6 loads per tile: A j0,A j1,B j0 in P1; A j2,A j3,B j1 in P2):
//   prologue: stage T0(6), T1(6); vmcnt(6) retires T0.
//   iter t:   stage T+2(6); boundary vmcnt(6) retires T+1 (never 0 in loop);
//             t==NT-2: nothing staged, vmcnt(0) retires T_{NT-1}; t==NT-1: none.
#define BMq 256
#define BNq 128
#define BKq 32

typedef short bf16x8 __attribute__((ext_vector_type(8)));
typedef float f32x4 __attribute__((ext_vector_type(4)));

__device__ __forceinline__ unsigned short f2bf(float f) {
  union { float f; unsigned u; } v; v.f = f;
  unsigned r = v.u + 0x7FFFu + ((v.u >> 16) & 1u);
  return (unsigned short)(r >> 16);
}

__device__ __forceinline__ void gload16(const unsigned short* g, unsigned short* l) {
  __builtin_amdgcn_global_load_lds(
      (const __attribute__((address_space(1))) unsigned int*)g,
      (__attribute__((address_space(3))) unsigned int*)l,
      16, 0, 0);
}

// ---------------- x fp32 -> bf16 ----------------
__global__ void xconv_kernel(const float* __restrict__ x, unsigned short* __restrict__ xb) {
  const int i = (blockIdx.x * 256 + threadIdx.x) * 8;
  const float4 v0 = *(const float4*)(x + i);
  const float4 v1 = *(const float4*)(x + i + 4);
  bf16x8 o;
  o[0] = (short)f2bf(v0.x); o[1] = (short)f2bf(v0.y);
  o[2] = (short)f2bf(v0.z); o[3] = (short)f2bf(v0.w);
  o[4] = (short)f2bf(v1.x); o[5] = (short)f2bf(v1.y);
  o[6] = (short)f2bf(v1.z); o[7] = (short)f2bf(v1.w);
  *(bf16x8*)(xb + i) = o;
}

// ---------------- prep: transpose + convert; gate/up INTERLEAVED -----------
// gu dst row 2f+0 = gate feature f, 2f+1 = up feature f (stride Hd).
// down dst unchanged: [Hd][Fd].
__global__ void prep_transpose_kernel(const float* __restrict__ gw,
                                      const float* __restrict__ uw,
                                      const float* __restrict__ dw,
                                      unsigned short* __restrict__ gu,
                                      unsigned short* __restrict__ dt) {
  const int m = blockIdx.z % 3;
  const int e = blockIdx.z / 3;
  const int R = (m == 2) ? Fd : Hd;   // src rows (= dst stride)
  const int C = (m == 2) ? Hd : Fd;   // src cols
  const int r0 = blockIdx.y * 64, c0 = blockIdx.x * 64;
  if (r0 >= R || c0 >= C) return;
  const float* src = ((m == 0) ? gw : (m == 1) ? uw : dw) + (size_t)e * Hd * Fd;
  __shared__ unsigned short tile[64][68];
  const int tr = threadIdx.x >> 4;
  const int tc = (threadIdx.x & 15) * 4;
#pragma unroll
  for (int i = 0; i < 4; ++i) {
    const int r = tr + i * 16;
    const float4 v = *(const float4*)(src + (size_t)(r0 + r) * C + c0 + tc);
    tile[r][tc + 0] = f2bf(v.x);
    tile[r][tc + 1] = f2bf(v.y);
    tile[r][tc + 2] = f2bf(v.z);
    tile[r][tc + 3] = f2bf(v.w);
  }
  __syncthreads();
#pragma unroll
  for (int i = 0; i < 4; ++i) {
    const int c = tr + i * 16;   // src col = feature index
    ushort4 o;
    o.x = tile[tc + 0][c];
    o.y = tile[tc + 1][c];
    o.z = tile[tc + 2][c];
    o.w = tile[tc + 3][c];
    size_t drow = (m == 2) ? (size_t)(c0 + c) : (size_t)(2 * (c0 + c) + m);
    unsigned short* dst = (m == 2) ? (dt + (size_t)e * Hd * Fd)
                                   : (gu + (size_t)e * 2 * Fd * Hd);
    *(ushort4*)(dst + drow * R + r0 + tc) = o;
  }
}

// ---------------- routing: wave-aggregated per-expert lists ----------------
__global__ void routing_kernel(const int* __restrict__ ids,
                               const float* __restrict__ w,
                               int* __restrict__ cnt, int* __restrict__ base,
                               int* __restrict__ tok, float* __restrict__ cof) {
  __shared__ int lcnt[Ed], lbase[Ed], lpos[Ed];
  const int t = threadIdx.x;
  const int lane = t & 63;
  if (t < Ed) { lcnt[t] = 0; lpos[t] = 0; }
  __syncthreads();
  for (int i = t; i < Td; i += 1024) {
    const int e0 = ids[2 * i], e1 = ids[2 * i + 1];
    const int em = (e1 == e0) ? -1 : e1;
#pragma unroll
    for (int e = 0; e < Ed; ++e) {
      unsigned long long m0 = __ballot(e0 == e);
      unsigned long long m1 = __ballot(em == e);
      int n = __popcll(m0) + __popcll(m1);
      if (lane == 0 && n) atomicAdd(&lcnt[e], n);
    }
  }
  __syncthreads();
  if (t == 0) {
    int s = 0;
    for (int e = 0; e < Ed; ++e) { lbase[e] = s; s += lcnt[e]; }
  }
  __syncthreads();
  const unsigned long long below = (1ull << lane) - 1ull;
  for (int i = t; i < Td; i += 1024) {
    const int e0 = ids[2 * i], e1 = ids[2 * i + 1];
    const float w0 = w[2 * i], w1 = w[2 * i + 1];
    const bool mg = (e1 == e0);
    const int em = mg ? -1 : e1;
#pragma unroll
    for (int e = 0; e < Ed; ++e) {
      unsigned long long m0 = __ballot(e0 == e);
      unsigned long long m1 = __ballot(em == e);
      const int n0 = __popcll(m0);
      const int n = n0 + __popcll(m1);
      int p = 0;
      if (lane == 0 && n) p = atomicAdd(&lpos[e], n);
      p = __shfl(p, 0);
      if (e0 == e) {
        const int r = lbase[e] + p + __popcll(m0 & below);
        tok[r] = i; cof[r] = mg ? (w0 + w1) : w0;
      }
      if (em == e) {
        const int r = lbase[e] + p + n0 + __popcll(m1 & below);
        tok[r] = i; cof[r] = w1;
      }
    }
  }
  __syncthreads();
  if (t < Ed) { cnt[t] = lcnt[t]; base[t] = lbase[t]; }
}

// swizzle: lds 16B-slot sl within row (4 slots, BK=32) holds global k-group
// g = sl ^ ((row>>1)&3). 16-lane b128 reads land 2-way per bank (free, m136).

// ---------------- gateup: pipelined grouped GEMM, N = interleaved 2F --------
__global__ __launch_bounds__(256, 2)
void gateup_kernel(const unsigned short* __restrict__ xb,
                   const unsigned short* __restrict__ gu_t,
                   const int* __restrict__ cnt, const int* __restrict__ base,
                   const int* __restrict__ tok, const float* __restrict__ cof,
                   unsigned short* __restrict__ act) {
  const int e = blockIdx.z, mt = blockIdx.y, nt = blockIdx.x;
  const int cn = cnt[e];
  if (mt * BMq >= cn) return;
  const int b0 = base[e];

  __shared__ unsigned short A_l[3][BMq * BKq];
  __shared__ unsigned short B_l[3][BNq * BKq];
  __shared__ int tok_l[BMq];
  __shared__ float cof_l[BMq];

  const int tid = threadIdx.x, lane = tid & 63, wave = tid >> 6;
  {
    const int r = mt * BMq + tid;
    tok_l[tid] = (r < cn) ? tok[b0 + r] : tok[b0];
    cof_l[tid] = (r < cn) ? cof[b0 + r] : 0.f;
  }
  __syncthreads();

  // staging sources (per-lane, inverse-swizzled k-group)
  const unsigned short* gup = gu_t + (size_t)e * 2 * Fd * Hd + (size_t)(nt * BNq) * Hd;
  const unsigned short* aS[4];
  const unsigned short* bS[2];
#pragma unroll
  for (int j = 0; j < 4; ++j) {
    const int s = tid + j * 256;
    const int row = s >> 2, g = (s & 3) ^ ((row >> 1) & 3);
    aS[j] = xb + (size_t)tok_l[row] * Hd + g * 8;
  }
#pragma unroll
  for (int j = 0; j < 2; ++j) {
    const int s = tid + j * 256;
    const int row = s >> 2, g = (s & 3) ^ ((row >> 1) & 3);
    bS[j] = gup + (size_t)row * Hd + g * 8;
  }
  const int dstA = wave * 512;  // + j*2048 ; lane offset is implicit (HW lane*16B)
  const int dstB = wave * 512;

  // fragment LDS element offsets
  const int fr16 = lane & 15, kg = lane >> 4;
  const int wm = wave >> 1, wn = wave & 1;
  int aOff[8], bOff[4];
#pragma unroll
  for (int rf = 0; rf < 8; ++rf) {
    const int r = wm * 128 + rf * 16 + fr16;
    aOff[rf] = r * 32 + ((kg ^ ((r >> 1) & 3)) * 8);
  }
#pragma unroll
  for (int cf = 0; cf < 4; ++cf) {
    const int r = wn * 64 + cf * 16 + fr16;
    bOff[cf] = r * 32 + ((kg ^ ((r >> 1) & 3)) * 8);
  }

  f32x4 acc[8][4];
#pragma unroll
  for (int i = 0; i < 8; ++i)
#pragma unroll
    for (int j = 0; j < 4; ++j) acc[i][j] = (f32x4){0.f, 0.f, 0.f, 0.f};

  const int NT = Hd / BKq;  // 32
  // prologue: stage tile0 -> slot0, tile1 -> slot1
#pragma unroll
  for (int j = 0; j < 4; ++j) gload16(aS[j] + 0, &A_l[0][j * 2048 + dstA]);
#pragma unroll
  for (int j = 0; j < 2; ++j) gload16(bS[j] + 0, &B_l[0][j * 2048 + dstB]);
#pragma unroll
  for (int j = 0; j < 4; ++j) gload16(aS[j] + BKq, &A_l[1][j * 2048 + dstA]);
#pragma unroll
  for (int j = 0; j < 2; ++j) gload16(bS[j] + BKq, &B_l[1][j * 2048 + dstB]);
  asm volatile("s_waitcnt vmcnt(6)" ::: "memory");
  __builtin_amdgcn_s_barrier();

  for (int t = 0; t < NT; ++t) {
    const int sl = t % 3, sn = (t + 2) % 3;
    const bool st = (t + 2) < NT;
    const int kn = (t + 2) * BKq;
    const unsigned short* Ab = &A_l[sl][0];
    const unsigned short* Bb = &B_l[sl][0];
    // ---- phase 1: frags rf0..3 + all B; stage A0,A1,B0 of tile t+2
    bf16x8 av[4], bv[4];
#pragma unroll
    for (int rf = 0; rf < 4; ++rf) av[rf] = *(const bf16x8*)(Ab + aOff[rf]);
#pragma unroll
    for (int cf = 0; cf < 4; ++cf) bv[cf] = *(const bf16x8*)(Bb + bOff[cf]);
    if (st) {
      gload16(aS[0] + kn, &A_l[sn][0 * 2048 + dstA]);
      gload16(aS[1] + kn, &A_l[sn][1 * 2048 + dstA]);
      gload16(bS[0] + kn, &B_l[sn][0 * 2048 + dstB]);
    }
    __builtin_amdgcn_s_barrier();
    asm volatile("s_waitcnt lgkmcnt(0)" ::: "memory");
    __builtin_amdgcn_sched_barrier(0);
    __builtin_amdgcn_s_setprio(1);
#pragma unroll
    for (int rf = 0; rf < 4; ++rf)
#pragma unroll
      for (int cf = 0; cf < 4; ++cf)
        acc[rf][cf] = __builtin_amdgcn_mfma_f32_16x16x32_bf16(av[rf], bv[cf], acc[rf][cf], 0, 0, 0);
    __builtin_amdgcn_s_setprio(0);
    __builtin_amdgcn_s_barrier();
    // ---- phase 2: frags rf4..7; stage A2,A3,B1 of tile t+2
    bf16x8 aw[4];
#pragma unroll
    for (int rf = 0; rf < 4; ++rf) aw[rf] = *(const bf16x8*)(Ab + aOff[4 + rf]);
    if (st) {
      gload16(aS[2] + kn, &A_l[sn][2 * 2048 + dstA]);
      gload16(aS[3] + kn, &A_l[sn][3 * 2048 + dstA]);
      gload16(bS[1] + kn, &B_l[sn][1 * 2048 + dstB]);
    }
    __builtin_amdgcn_s_barrier();
    asm volatile("s_waitcnt lgkmcnt(0)" ::: "memory");
    __builtin_amdgcn_sched_barrier(0);
    __builtin_amdgcn_s_setprio(1);
#pragma unroll
    for (int rf = 0; rf < 4; ++rf)
#pragma unroll
      for (int cf = 0; cf < 4; ++cf)
        acc[4 + rf][cf] = __builtin_amdgcn_mfma_f32_16x16x32_bf16(aw[rf], bv[cf], acc[4 + rf][cf], 0, 0, 0);
    __builtin_amdgcn_s_setprio(0);
    if (t < NT - 2)       asm volatile("s_waitcnt vmcnt(6)" ::: "memory");
    else if (t == NT - 2) asm volatile("s_waitcnt vmcnt(0)" ::: "memory");
    __builtin_amdgcn_s_barrier();
  }

  // epilogue: pair g/u across adjacent lanes, silu*u*coeff, even lane stores
  const int row4 = (lane >> 4) * 4;
  const int colbase = nt * BNq + wn * 64;
#pragma unroll
  for (int rf = 0; rf < 8; ++rf) {
#pragma unroll
    for (int cf = 0; cf < 4; ++cf) {
#pragma unroll
      for (int r = 0; r < 4; ++r) {
        const int rr = wm * 128 + rf * 16 + row4 + r;
        const int grow = mt * BMq + rr;
        const float v = acc[rf][cf][r];
        const float p = __shfl_xor(v, 1);
        const float g = (lane & 1) ? p : v;
        const float u = (lane & 1) ? v : p;
        if (grow < cn && !(lane & 1)) {
          const float a = (g / (1.f + __expf(-g))) * u * cof_l[rr];
          const int col = colbase + cf * 16 + fr16;   // even
          act[(size_t)(b0 + grow) * Fd + (col >> 1)] = f2bf(a);
        }
      }
    }
  }
}

// ---------------- down: pipelined grouped GEMM, split-K, atomic scatter -----
__global__ __launch_bounds__(256, 2)
void down_kernel(const unsigned short* __restrict__ act,
                 const unsigned short* __restrict__ down_t,
                 const int* __restrict__ cnt, const int* __restrict__ base,
                 const int* __restrict__ tok,
                 float* __restrict__ out) {
  const int nt = blockIdx.x & 7, kc = blockIdx.x >> 3;
  const int e = blockIdx.z, mt = blockIdx.y;
  const int cn = cnt[e];
  if (mt * BMq >= cn) return;
  const int b0 = base[e];

  __shared__ unsigned short A_l[3][BMq * BKq];
  __shared__ unsigned short B_l[3][BNq * BKq];
  __shared__ int tok_l[BMq];

  const int tid = threadIdx.x, lane = tid & 63, wave = tid >> 6;
  {
    const int r = mt * BMq + tid;
    tok_l[tid] = (r < cn) ? tok[b0 + r] : tok[b0];
  }
  __syncthreads();

  const int kbase = kc * (Fd / 2);
  const unsigned short* dwp = down_t + (size_t)e * Hd * Fd + (size_t)(nt * BNq) * Fd + kbase;
  const unsigned short* aS[4];
  const unsigned short* bS[2];
#pragma unroll
  for (int j = 0; j < 4; ++j) {
    const int s = tid + j * 256;
    const int row = s >> 2, g = (s & 3) ^ ((row >> 1) & 3);
    int ar = b0 + mt * BMq + row;
    if (ar > 8191) ar = 8191;
    aS[j] = act + (size_t)ar * Fd + kbase + g * 8;
  }
#pragma unroll
  for (int j = 0; j < 2; ++j) {
    const int s = tid + j * 256;
    const int row = s >> 2, g = (s & 3) ^ ((row >> 1) & 3);
    bS[j] = dwp + (size_t)row * Fd + g * 8;
  }
  const int dstA = wave * 512, dstB = wave * 512;

  const int fr16 = lane & 15, kg = lane >> 4;
  const int wm = wave >> 1, wn = wave & 1;
  int aOff[8], bOff[4];
#pragma unroll
  for (int rf = 0; rf < 8; ++rf) {
    const int r = wm * 128 + rf * 16 + fr16;
    aOff[rf] = r * 32 + ((kg ^ ((r >> 1) & 3)) * 8);
  }
#pragma unroll
  for (int cf = 0; cf < 4; ++cf) {
    const int r = wn * 64 + cf * 16 + fr16;
    bOff[cf] = r * 32 + ((kg ^ ((r >> 1) & 3)) * 8);
  }

  f32x4 acc[8][4];
#pragma unroll
  for (int i = 0; i < 8; ++i)
#pragma unroll
    for (int j = 0; j < 4; ++j) acc[i][j] = (f32x4){0.f, 0.f, 0.f, 0.f};

  const int NT = (Fd / 2) / BKq;  // 32
#pragma unroll
  for (int j = 0; j < 4; ++j) gload16(aS[j] + 0, &A_l[0][j * 2048 + dstA]);
#pragma unroll
  for (int j = 0; j < 2; ++j) gload16(bS[j] + 0, &B_l[0][j * 2048 + dstB]);
#pragma unroll
  for (int j = 0; j < 4; ++j) gload16(aS[j] + BKq, &A_l[1][j * 2048 + dstA]);
#pragma unroll
  for (int j = 0; j < 2; ++j) gload16(bS[j] + BKq, &B_l[1][j * 2048 + dstB]);
  asm volatile("s_waitcnt vmcnt(6)" ::: "memory");
  __builtin_amdgcn_s_barrier();

  for (int t = 0; t < NT; ++t) {
    const int sl = t % 3, sn = (t + 2) % 3;
    const bool st = (t + 2) < NT;
    const int kn = (t + 2) * BKq;
    const unsigned short* Ab = &A_l[sl][0];
    const unsigned short* Bb = &B_l[sl][0];
    bf16x8 av[4], bv[4];
#pragma unroll
    for (int rf = 0; rf < 4; ++rf) av[rf] = *(const bf16x8*)(Ab + aOff[rf]);
#pragma unroll
    for (int cf = 0; cf < 4; ++cf) bv[cf] = *(const bf16x8*)(Bb + bOff[cf]);
    if (st) {
      gload16(aS[0] + kn, &A_l[sn][0 * 2048 + dstA]);
      gload16(aS[1] + kn, &A_l[sn][1 * 2048 + dstA]);
      gload16(bS[0] + kn, &B_l[sn][0 * 2048 + dstB]);
    }
    __builtin_amdgcn_s_barrier();
    asm volatile("s_waitcnt lgkmcnt(0)" ::: "memory");
    __builtin_amdgcn_sched_barrier(0);
    __builtin_amdgcn_s_setprio(1);
#pragma unroll
    for (int rf = 0; rf < 4; ++rf)
#pragma unroll
      for (int cf = 0; cf < 4; ++cf)
        acc[rf][cf] = __builtin_amdgcn_mfma_f32_16x16x32_bf16(av[rf], bv[cf], acc[rf][cf], 0, 0, 0);
    __builtin_amdgcn_s_setprio(0);
    __builtin_amdgcn_s_barrier();
    bf16x8 aw[4];
#pragma unroll
    for (int rf = 0; rf < 4; ++rf) aw[rf] = *(const bf16x8*)(Ab + aOff[4 + rf]);
    if (st) {
      gload16(aS[2] + kn, &A_l[sn][2 * 2048 + dstA]);
      gload16(aS[3] + kn, &A_l[sn][3 * 2048 + dstA]);
      gload16(bS[1] + kn, &B_l[sn][1 * 2048 + dstB]);
    }
    __builtin_amdgcn_s_barrier();
    asm volatile("s_waitcnt lgkmcnt(0)" ::: "memory");
    __builtin_amdgcn_sched_barrier(0);
    __builtin_amdgcn_s_setprio(1);
#pragma unroll
    for (int rf = 0; rf < 4; ++rf)
#pragma unroll
      for (int cf = 0; cf < 4; ++cf)
        acc[4 + rf][cf] = __builtin_amdgcn_mfma_f32_16x16x32_bf16(aw[rf], bv[cf], acc[4 + rf][cf], 0, 0, 0);
    __builtin_amdgcn_s_setprio(0);
    if (t < NT - 2)       asm volatile("s_waitcnt vmcnt(6)" ::: "memory");
    else if (t == NT - 2) asm volatile("s_waitcnt vmcnt(0)" ::: "memory");
    __builtin_amdgcn_s_barrier();
  }

  const int row4 = (lane >> 4) * 4;
  const int colbase = nt * BNq + wn * 64;
#pragma unroll
  for (int rf = 0; rf < 8; ++rf) {
#pragma unroll
    for (int cf = 0; cf < 4; ++cf) {
#pragma unroll
      for (int r = 0; r < 4; ++r) {
        const int rr = wm * 128 + rf * 16 + row4 + r;
        if (mt * BMq + rr < cn) {
          const int col = colbase + cf * 16 + fr16;
          atomicAdd(&out[(size_t)tok_l[rr] * Hd + col], acc[rf][cf][r]);
        }
      }
    }
  }
}

extern "C" void kernel_launch(void* const* d_in, const int* in_sizes, int n_in,
                              void* d_out, int out_size, void* d_ws, size_t ws_size,
                              hipStream_t stream) {
  const float* x  = (const float*)d_in[0];
  const int*   ids = (const int*)d_in[1];
  const float* w  = (const float*)d_in[2];
  const float* gw = (const float*)d_in[3];
  const float* uw = (const float*)d_in[4];
  const float* dw = (const float*)d_in[5];
  float* out = (float*)d_out;

  // ws: gu_t (64MB interleaved) | dt (32MB) | act (32MB) | xb (8MB) | meta
  const size_t SZW = (size_t)Ed * Hd * Fd * 2;
  const size_t ACT = (size_t)8192 * Fd * 2;
  const size_t XB  = (size_t)Td * Hd * 2;
  const size_t NEED = 3 * SZW + ACT + XB + 1 * 1024 * 1024;
  if (ws_size < NEED) return;

  char* ws = (char*)d_ws;
  unsigned short* gu   = (unsigned short*)(ws);             // 2*SZW
  unsigned short* dt   = (unsigned short*)(ws + 2 * SZW);
  unsigned short* act  = (unsigned short*)(ws + 3 * SZW);
  unsigned short* xbuf = (unsigned short*)(ws + 3 * SZW + ACT);
  char* meta = ws + 3 * SZW + ACT + XB;
  int*   cnt  = (int*)meta;
  int*   base = (int*)(meta + 32);
  int*   tok  = (int*)(meta + 64);
  float* cof  = (float*)(meta + 64 + 8192 * 4);

  hipMemsetAsync(d_out, 0, (size_t)Td * Hd * 4, stream);
  xconv_kernel<<<Td * Hd / 8 / 256, 256, 0, stream>>>(x, xbuf);
  routing_kernel<<<1, 1024, 0, stream>>>(ids, w, cnt, base, tok, cof);
  prep_transpose_kernel<<<dim3(32, 32, 24), 256, 0, stream>>>(gw, uw, dw, gu, dt);
  gateup_kernel<<<dim3(2 * Fd / BNq, Td * 2 / BMq, Ed), 256, 0, stream>>>(xbuf, gu, cnt, base, tok, cof, act);
  down_kernel<<<dim3((Hd / BNq) * 2, Td * 2 / BMq, Ed), 256, 0, stream>>>(act, dt, cnt, base, tok, out);
}

// Round 6
// 424.892 us; speedup vs baseline: 1.2115x; 1.0088x over previous
//
#include <hip/hip_runtime.h>
#include <hip/hip_bf16.h>

#define Td 4096
#define Hd 1024
#define Fd 2048
#define Ed 8

// GEMM geometry: 256x256 tile, BK=32, 512 threads = 8 waves (2m x 4n),
// wave tile = 128x64. LDS: 4-slot ring (A,B each 256x32 bf16 = 16KB -> 32KB/slot,
// 128KB total, 1 block/CU, 2 waves/SIMD). Prefetch depth 3.
// vmcnt ledger (4 loads per tile per thread: A j0,j1 in P1; B j0,j1 in P2):
//   prologue: stage T0,T1,T2 (12 loads); vmcnt(8) retires T0.
//   iter t: stage T+3 (A in P1, B in P2); boundary:
//     t+3<NT: vmcnt(8) retires T+1 (T+2,T+3 stay in flight — never 0 in loop)
//     t+2<NT: vmcnt(4) ; t+1<NT: vmcnt(0) ; else none.
#define BMq 256
#define BNq 256
#define BKq 32
#define MAXT 40

typedef short bf16x8 __attribute__((ext_vector_type(8)));
typedef float f32x4 __attribute__((ext_vector_type(4)));

__device__ __forceinline__ unsigned short f2bf(float f) {
  union { float f; unsigned u; } v; v.f = f;
  unsigned r = v.u + 0x7FFFu + ((v.u >> 16) & 1u);
  return (unsigned short)(r >> 16);
}

__device__ __forceinline__ void gload16(const unsigned short* g, unsigned short* l) {
  __builtin_amdgcn_global_load_lds(
      (const __attribute__((address_space(1))) unsigned int*)g,
      (__attribute__((address_space(3))) unsigned int*)l,
      16, 0, 0);
}

// ---------------- x fp32 -> bf16 ----------------
__global__ void xconv_kernel(const float* __restrict__ x, unsigned short* __restrict__ xb) {
  const int i = (blockIdx.x * 256 + threadIdx.x) * 8;
  const float4 v0 = *(const float4*)(x + i);
  const float4 v1 = *(const float4*)(x + i + 4);
  bf16x8 o;
  o[0] = (short)f2bf(v0.x); o[1] = (short)f2bf(v0.y);
  o[2] = (short)f2bf(v0.z); o[3] = (short)f2bf(v0.w);
  o[4] = (short)f2bf(v1.x); o[5] = (short)f2bf(v1.y);
  o[6] = (short)f2bf(v1.z); o[7] = (short)f2bf(v1.w);
  *(bf16x8*)(xb + i) = o;
}

// ---------------- prep: transpose + convert; gate/up INTERLEAVED -----------
__global__ void prep_transpose_kernel(const float* __restrict__ gw,
                                      const float* __restrict__ uw,
                                      const float* __restrict__ dw,
                                      unsigned short* __restrict__ gu,
                                      unsigned short* __restrict__ dt) {
  const int m = blockIdx.z % 3;
  const int e = blockIdx.z / 3;
  const int R = (m == 2) ? Fd : Hd;   // src rows (= dst row length)
  const int C = (m == 2) ? Hd : Fd;   // src cols
  const int r0 = blockIdx.y * 64, c0 = blockIdx.x * 64;
  if (r0 >= R || c0 >= C) return;
  const float* src = ((m == 0) ? gw : (m == 1) ? uw : dw) + (size_t)e * Hd * Fd;
  __shared__ unsigned short tile[64][68];
  const int tr = threadIdx.x >> 4;
  const int tc = (threadIdx.x & 15) * 4;
#pragma unroll
  for (int i = 0; i < 4; ++i) {
    const int r = tr + i * 16;
    const float4 v = *(const float4*)(src + (size_t)(r0 + r) * C + c0 + tc);
    tile[r][tc + 0] = f2bf(v.x);
    tile[r][tc + 1] = f2bf(v.y);
    tile[r][tc + 2] = f2bf(v.z);
    tile[r][tc + 3] = f2bf(v.w);
  }
  __syncthreads();
#pragma unroll
  for (int i = 0; i < 4; ++i) {
    const int c = tr + i * 16;   // src col = feature index
    ushort4 o;
    o.x = tile[tc + 0][c];
    o.y = tile[tc + 1][c];
    o.z = tile[tc + 2][c];
    o.w = tile[tc + 3][c];
    size_t drow = (m == 2) ? (size_t)(c0 + c) : (size_t)(2 * (c0 + c) + m);
    unsigned short* dst = (m == 2) ? (dt + (size_t)e * Hd * Fd)
                                   : (gu + (size_t)e * 2 * Fd * Hd);
    *(ushort4*)(dst + drow * R + r0 + tc) = o;
  }
}

// ---------------- routing + flat tile list ----------------
__global__ void routing_kernel(const int* __restrict__ ids,
                               const float* __restrict__ w,
                               int* __restrict__ cnt, int* __restrict__ base,
                               int* __restrict__ tok, float* __restrict__ cof,
                               int* __restrict__ tle, int* __restrict__ tlrb,
                               int* __restrict__ ntile) {
  __shared__ int lcnt[Ed], lbase[Ed], lpos[Ed];
  const int t = threadIdx.x;
  const int lane = t & 63;
  if (t < Ed) { lcnt[t] = 0; lpos[t] = 0; }
  __syncthreads();
  for (int i = t; i < Td; i += 1024) {
    const int e0 = ids[2 * i], e1 = ids[2 * i + 1];
    const int em = (e1 == e0) ? -1 : e1;
#pragma unroll
    for (int e = 0; e < Ed; ++e) {
      unsigned long long m0 = __ballot(e0 == e);
      unsigned long long m1 = __ballot(em == e);
      int n = __popcll(m0) + __popcll(m1);
      if (lane == 0 && n) atomicAdd(&lcnt[e], n);
    }
  }
  __syncthreads();
  if (t == 0) {
    int s = 0, nt = 0;
    for (int e = 0; e < Ed; ++e) {
      lbase[e] = s; s += lcnt[e];
      for (int rb = 0; rb < lcnt[e]; rb += BMq) { tle[nt] = e; tlrb[nt] = rb; ++nt; }
    }
    *ntile = nt;
  }
  __syncthreads();
  const unsigned long long below = (1ull << lane) - 1ull;
  for (int i = t; i < Td; i += 1024) {
    const int e0 = ids[2 * i], e1 = ids[2 * i + 1];
    const float w0 = w[2 * i], w1 = w[2 * i + 1];
    const bool mg = (e1 == e0);
    const int em = mg ? -1 : e1;
#pragma unroll
    for (int e = 0; e < Ed; ++e) {
      unsigned long long m0 = __ballot(e0 == e);
      unsigned long long m1 = __ballot(em == e);
      const int n0 = __popcll(m0);
      const int n = n0 + __popcll(m1);
      int p = 0;
      if (lane == 0 && n) p = atomicAdd(&lpos[e], n);
      p = __shfl(p, 0);
      if (e0 == e) {
        const int r = lbase[e] + p + __popcll(m0 & below);
        tok[r] = i; cof[r] = mg ? (w0 + w1) : w0;
      }
      if (em == e) {
        const int r = lbase[e] + p + n0 + __popcll(m1 & below);
        tok[r] = i; cof[r] = w1;
      }
    }
  }
  __syncthreads();
  if (t < Ed) { cnt[t] = lcnt[t]; base[t] = lbase[t]; }
}

// swizzle: lds 16B-group sl within row (4 groups, BK=32) holds global k-group
// g = sl ^ ((row>>1)&3); measured 0 bank conflicts (round 3/4).

// ---------------- gateup: 256x256 pipelined grouped GEMM -------------------
__global__ __launch_bounds__(512, 2)
void gateup_kernel(const unsigned short* __restrict__ xb,
                   const unsigned short* __restrict__ gu_t,
                   const int* __restrict__ cnt, const int* __restrict__ base,
                   const int* __restrict__ tok, const float* __restrict__ cof,
                   const int* __restrict__ tle, const int* __restrict__ tlrb,
                   const int* __restrict__ ntile,
                   unsigned short* __restrict__ act) {
  const int mt = blockIdx.y;
  if (mt >= *ntile) return;
  const int e = tle[mt], rb = tlrb[mt], nt = blockIdx.x;
  const int cn = cnt[e], b0 = base[e];

  __shared__ unsigned short A_l[4][BMq * BKq];
  __shared__ unsigned short B_l[4][BNq * BKq];
  __shared__ int tok_l[BMq];
  __shared__ float cof_l[BMq];

  const int tid = threadIdx.x, lane = tid & 63, wave = tid >> 6;
  if (tid < BMq) {
    const int r = rb + tid;
    tok_l[tid] = (r < cn) ? tok[b0 + r] : tok[b0];
    cof_l[tid] = (r < cn) ? cof[b0 + r] : 0.f;
  }
  __syncthreads();

  // staging sources: chunk s = tid + j*512; row = s>>2, group = (s&3)^((row>>1)&3)
  const unsigned short* gup = gu_t + (size_t)e * 2 * Fd * Hd + (size_t)(nt * BNq) * Hd;
  const unsigned short* aS[2];
  const unsigned short* bS[2];
#pragma unroll
  for (int j = 0; j < 2; ++j) {
    const int s = tid + j * 512;
    const int row = s >> 2, g = (s & 3) ^ ((row >> 1) & 3);
    aS[j] = xb + (size_t)tok_l[row] * Hd + g * 8;
    bS[j] = gup + (size_t)row * Hd + g * 8;
  }
  const int dst0 = wave * 512;          // elems; + j*4096; HW adds lane*16B

  const int fr16 = lane & 15, kg = lane >> 4;
  const int wm = wave >> 2, wn = wave & 3;
  int aOff[8], bOff[4];
#pragma unroll
  for (int rf = 0; rf < 8; ++rf) {
    const int r = wm * 128 + rf * 16 + fr16;
    aOff[rf] = r * 32 + ((kg ^ ((r >> 1) & 3)) * 8);
  }
#pragma unroll
  for (int cf = 0; cf < 4; ++cf) {
    const int r = wn * 64 + cf * 16 + fr16;
    bOff[cf] = r * 32 + ((kg ^ ((r >> 1) & 3)) * 8);
  }

  f32x4 acc[8][4];
#pragma unroll
  for (int i = 0; i < 8; ++i)
#pragma unroll
    for (int j = 0; j < 4; ++j) acc[i][j] = (f32x4){0.f, 0.f, 0.f, 0.f};

  const int NT = Hd / BKq;  // 32
  // prologue: stage T0,T1,T2
#pragma unroll
  for (int p = 0; p < 3; ++p) {
#pragma unroll
    for (int j = 0; j < 2; ++j) gload16(aS[j] + p * BKq, &A_l[p][dst0 + j * 4096]);
#pragma unroll
    for (int j = 0; j < 2; ++j) gload16(bS[j] + p * BKq, &B_l[p][dst0 + j * 4096]);
  }
  asm volatile("s_waitcnt vmcnt(8)" ::: "memory");
  __builtin_amdgcn_s_barrier();

  for (int t = 0; t < NT; ++t) {
    const int sl = t & 3, sn = (t + 3) & 3;
    const bool st = (t + 3) < NT;
    const int kn = (t + 3) * BKq;
    const unsigned short* Ab = &A_l[sl][0];
    const unsigned short* Bb = &B_l[sl][0];
    // ---- phase 1: A-frags rf0..3 + all B-frags; stage A(T+3)
    bf16x8 av[4], bv[4];
#pragma unroll
    for (int rf = 0; rf < 4; ++rf) av[rf] = *(const bf16x8*)(Ab + aOff[rf]);
#pragma unroll
    for (int cf = 0; cf < 4; ++cf) bv[cf] = *(const bf16x8*)(Bb + bOff[cf]);
    if (st) {
      gload16(aS[0] + kn, &A_l[sn][dst0]);
      gload16(aS[1] + kn, &A_l[sn][dst0 + 4096]);
    }
    __builtin_amdgcn_s_barrier();
    asm volatile("s_waitcnt lgkmcnt(0)" ::: "memory");
    __builtin_amdgcn_sched_barrier(0);
    __builtin_amdgcn_s_setprio(1);
#pragma unroll
    for (int rf = 0; rf < 4; ++rf)
#pragma unroll
      for (int cf = 0; cf < 4; ++cf)
        acc[rf][cf] = __builtin_amdgcn_mfma_f32_16x16x32_bf16(av[rf], bv[cf], acc[rf][cf], 0, 0, 0);
    __builtin_amdgcn_s_setprio(0);
    __builtin_amdgcn_s_barrier();
    // ---- phase 2: A-frags rf4..7; stage B(T+3)
    bf16x8 aw[4];
#pragma unroll
    for (int rf = 0; rf < 4; ++rf) aw[rf] = *(const bf16x8*)(Ab + aOff[4 + rf]);
    if (st) {
      gload16(bS[0] + kn, &B_l[sn][dst0]);
      gload16(bS[1] + kn, &B_l[sn][dst0 + 4096]);
    }
    __builtin_amdgcn_s_barrier();
    asm volatile("s_waitcnt lgkmcnt(0)" ::: "memory");
    __builtin_amdgcn_sched_barrier(0);
    __builtin_amdgcn_s_setprio(1);
#pragma unroll
    for (int rf = 0; rf < 4; ++rf)
#pragma unroll
      for (int cf = 0; cf < 4; ++cf)
        acc[4 + rf][cf] = __builtin_amdgcn_mfma_f32_16x16x32_bf16(aw[rf], bv[cf], acc[4 + rf][cf], 0, 0, 0);
    __builtin_amdgcn_s_setprio(0);
    if (st)                   asm volatile("s_waitcnt vmcnt(8)" ::: "memory");
    else if ((t + 2) < NT)    asm volatile("s_waitcnt vmcnt(4)" ::: "memory");
    else if ((t + 1) < NT)    asm volatile("s_waitcnt vmcnt(0)" ::: "memory");
    __builtin_amdgcn_s_barrier();
  }

  // epilogue: pair g/u across adjacent lanes, silu*u*coeff, even lane stores
  const int row4 = (lane >> 4) * 4;
  const int colbase = nt * BNq + wn * 64;
#pragma unroll
  for (int rf = 0; rf < 8; ++rf) {
#pragma unroll
    for (int cf = 0; cf < 4; ++cf) {
#pragma unroll
      for (int r = 0; r < 4; ++r) {
        const int rr = wm * 128 + rf * 16 + row4 + r;
        const int grow = rb + rr;
        const float v = acc[rf][cf][r];
        const float p = __shfl_xor(v, 1);
        const float g = (lane & 1) ? p : v;
        const float u = (lane & 1) ? v : p;
        if (grow < cn && !(lane & 1)) {
          const float a = (g / (1.f + __expf(-g))) * u * cof_l[rr];
          const int col = colbase + cf * 16 + fr16;   // even
          act[(size_t)(b0 + grow) * Fd + (col >> 1)] = f2bf(a);
        }
      }
    }
  }
}

// ---------------- down: 256x256 pipelined GEMM, split-K x2, atomic scatter --
__global__ __launch_bounds__(512, 2)
void down_kernel(const unsigned short* __restrict__ act,
                 const unsigned short* __restrict__ down_t,
                 const int* __restrict__ cnt, const int* __restrict__ base,
                 const int* __restrict__ tok,
                 const int* __restrict__ tle, const int* __restrict__ tlrb,
                 const int* __restrict__ ntile,
                 float* __restrict__ out) {
  const int mt = blockIdx.y;
  if (mt >= *ntile) return;
  const int e = tle[mt], rb = tlrb[mt];
  const int nt = blockIdx.x & 3, kc = blockIdx.x >> 2;
  const int cn = cnt[e], b0 = base[e];

  __shared__ unsigned short A_l[4][BMq * BKq];
  __shared__ unsigned short B_l[4][BNq * BKq];
  __shared__ int tok_l[BMq];

  const int tid = threadIdx.x, lane = tid & 63, wave = tid >> 6;
  if (tid < BMq) {
    const int r = rb + tid;
    tok_l[tid] = (r < cn) ? tok[b0 + r] : 0;
  }
  __syncthreads();

  const int kbase = kc * (Fd / 2);
  const unsigned short* dwp = down_t + (size_t)e * Hd * Fd + (size_t)(nt * BNq) * Fd + kbase;
  const unsigned short* aS[2];
  const unsigned short* bS[2];
#pragma unroll
  for (int j = 0; j < 2; ++j) {
    const int s = tid + j * 512;
    const int row = s >> 2, g = (s & 3) ^ ((row >> 1) & 3);
    int ar = b0 + rb + row;
    if (ar > 8191) ar = 8191;
    aS[j] = act + (size_t)ar * Fd + kbase + g * 8;
    bS[j] = dwp + (size_t)row * Fd + g * 8;
  }
  const int dst0 = wave * 512;

  const int fr16 = lane & 15, kg = lane >> 4;
  const int wm = wave >> 2, wn = wave & 3;
  int aOff[8], bOff[4];
#pragma unroll
  for (int rf = 0; rf < 8; ++rf) {
    const int r = wm * 128 + rf * 16 + fr16;
    aOff[rf] = r * 32 + ((kg ^ ((r >> 1) & 3)) * 8);
  }
#pragma unroll
  for (int cf = 0; cf < 4; ++cf) {
    const int r = wn * 64 + cf * 16 + fr16;
    bOff[cf] = r * 32 + ((kg ^ ((r >> 1) & 3)) * 8);
  }

  f32x4 acc[8][4];
#pragma unroll
  for (int i = 0; i < 8; ++i)
#pragma unroll
    for (int j = 0; j < 4; ++j) acc[i][j] = (f32x4){0.f, 0.f, 0.f, 0.f};

  const int NT = (Fd / 2) / BKq;  // 32
#pragma unroll
  for (int p = 0; p < 3; ++p) {
#pragma unroll
    for (int j = 0; j < 2; ++j) gload16(aS[j] + p * BKq, &A_l[p][dst0 + j * 4096]);
#pragma unroll
    for (int j = 0; j < 2; ++j) gload16(bS[j] + p * BKq, &B_l[p][dst0 + j * 4096]);
  }
  asm volatile("s_waitcnt vmcnt(8)" ::: "memory");
  __builtin_amdgcn_s_barrier();

  for (int t = 0; t < NT; ++t) {
    const int sl = t & 3, sn = (t + 3) & 3;
    const bool st = (t + 3) < NT;
    const int kn = (t + 3) * BKq;
    const unsigned short* Ab = &A_l[sl][0];
    const unsigned short* Bb = &B_l[sl][0];
    bf16x8 av[4], bv[4];
#pragma unroll
    for (int rf = 0; rf < 4; ++rf) av[rf] = *(const bf16x8*)(Ab + aOff[rf]);
#pragma unroll
    for (int cf = 0; cf < 4; ++cf) bv[cf] = *(const bf16x8*)(Bb + bOff[cf]);
    if (st) {
      gload16(aS[0] + kn, &A_l[sn][dst0]);
      gload16(aS[1] + kn, &A_l[sn][dst0 + 4096]);
    }
    __builtin_amdgcn_s_barrier();
    asm volatile("s_waitcnt lgkmcnt(0)" ::: "memory");
    __builtin_amdgcn_sched_barrier(0);
    __builtin_amdgcn_s_setprio(1);
#pragma unroll
    for (int rf = 0; rf < 4; ++rf)
#pragma unroll
      for (int cf = 0; cf < 4; ++cf)
        acc[rf][cf] = __builtin_amdgcn_mfma_f32_16x16x32_bf16(av[rf], bv[cf], acc[rf][cf], 0, 0, 0);
    __builtin_amdgcn_s_setprio(0);
    __builtin_amdgcn_s_barrier();
    bf16x8 aw[4];
#pragma unroll
    for (int rf = 0; rf < 4; ++rf) aw[rf] = *(const bf16x8*)(Ab + aOff[4 + rf]);
    if (st) {
      gload16(bS[0] + kn, &B_l[sn][dst0]);
      gload16(bS[1] + kn, &B_l[sn][dst0 + 4096]);
    }
    __builtin_amdgcn_s_barrier();
    asm volatile("s_waitcnt lgkmcnt(0)" ::: "memory");
    __builtin_amdgcn_sched_barrier(0);
    __builtin_amdgcn_s_setprio(1);
#pragma unroll
    for (int rf = 0; rf < 4; ++rf)
#pragma unroll
      for (int cf = 0; cf < 4; ++cf)
        acc[4 + rf][cf] = __builtin_amdgcn_mfma_f32_16x16x32_bf16(aw[rf], bv[cf], acc[4 + rf][cf], 0, 0, 0);
    __builtin_amdgcn_s_setprio(0);
    if (st)                   asm volatile("s_waitcnt vmcnt(8)" ::: "memory");
    else if ((t + 2) < NT)    asm volatile("s_waitcnt vmcnt(4)" ::: "memory");
    else if ((t + 1) < NT)    asm volatile("s_waitcnt vmcnt(0)" ::: "memory");
    __builtin_amdgcn_s_barrier();
  }

  const int row4 = (lane >> 4) * 4;
  const int colbase = nt * BNq + wn * 64;
#pragma unroll
  for (int rf = 0; rf < 8; ++rf) {
#pragma unroll
    for (int cf = 0; cf < 4; ++cf) {
#pragma unroll
      for (int r = 0; r < 4; ++r) {
        const int rr = wm * 128 + rf * 16 + row4 + r;
        if (rb + rr < cn) {
          const int col = colbase + cf * 16 + fr16;
          atomicAdd(&out[(size_t)tok_l[rr] * Hd + col], acc[rf][cf][r]);
        }
      }
    }
  }
}

extern "C" void kernel_launch(void* const* d_in, const int* in_sizes, int n_in,
                              void* d_out, int out_size, void* d_ws, size_t ws_size,
                              hipStream_t stream) {
  const float* x  = (const float*)d_in[0];
  const int*   ids = (const int*)d_in[1];
  const float* w  = (const float*)d_in[2];
  const float* gw = (const float*)d_in[3];
  const float* uw = (const float*)d_in[4];
  const float* dw = (const float*)d_in[5];
  float* out = (float*)d_out;

  const size_t SZW = (size_t)Ed * Hd * Fd * 2;
  const size_t ACT = (size_t)8192 * Fd * 2;
  const size_t XB  = (size_t)Td * Hd * 2;
  const size_t NEED = 3 * SZW + ACT + XB + 1 * 1024 * 1024;
  if (ws_size < NEED) return;

  char* ws = (char*)d_ws;
  unsigned short* gu   = (unsigned short*)(ws);             // 2*SZW interleaved gate/up
  unsigned short* dt   = (unsigned short*)(ws + 2 * SZW);
  unsigned short* act  = (unsigned short*)(ws + 3 * SZW);
  unsigned short* xbuf = (unsigned short*)(ws + 3 * SZW + ACT);
  char* meta = ws + 3 * SZW + ACT + XB;
  int*   cnt   = (int*)meta;
  int*   base  = (int*)(meta + 32);
  int*   tok   = (int*)(meta + 64);
  float* cof   = (float*)(meta + 64 + 8192 * 4);
  int*   tle   = (int*)(meta + 64 + 8192 * 8);
  int*   tlrb  = (int*)(meta + 64 + 8192 * 8 + MAXT * 4);
  int*   ntile = (int*)(meta + 64 + 8192 * 8 + 2 * MAXT * 4);

  hipMemsetAsync(d_out, 0, (size_t)Td * Hd * 4, stream);
  xconv_kernel<<<Td * Hd / 8 / 256, 256, 0, stream>>>(x, xbuf);
  routing_kernel<<<1, 1024, 0, stream>>>(ids, w, cnt, base, tok, cof, tle, tlrb, ntile);
  prep_transpose_kernel<<<dim3(32, 32, 24), 256, 0, stream>>>(gw, uw, dw, gu, dt);
  gateup_kernel<<<dim3(2 * Fd / BNq, MAXT), 512, 0, stream>>>(xbuf, gu, cnt, base, tok, cof, tle, tlrb, ntile, act);
  down_kernel<<<dim3((Hd / BNq) * 2, MAXT), 512, 0, stream>>>(act, dt, cnt, base, tok, tle, tlrb, ntile, out);
}